// Round 15
// baseline (196.867 us; speedup 1.0000x reference)
//
#include <hip/hip_runtime.h>
#include <hip/hip_bf16.h>

#define TDEPTH 6
#define NLEAF 64
#define NGATE 63
#define INF 512
#define OUTF 512
#define BATCH 1024
#define SPLITK 16
#define NPL 32        // real planes per K-slice (512/SPLITK)

typedef __attribute__((ext_vector_type(4)))  float f32x4;
typedef __attribute__((ext_vector_type(16))) float f32x16;
typedef __attribute__((ext_vector_type(8)))  __bf16 bf16x8;

__device__ __forceinline__ bf16x8 pack8(f32x4 a, f32x4 b) {
  bf16x8 w;
  w[0] = (__bf16)a[0]; w[1] = (__bf16)a[1];
  w[2] = (__bf16)a[2]; w[3] = (__bf16)a[3];
  w[4] = (__bf16)b[0]; w[5] = (__bf16)b[1];
  w[6] = (__bf16)b[2]; w[7] = (__bf16)b[3];
  return w;
}

// ---------------- kernel 1: leaf probs + fragment-major pwb pack ----------
// blocks [0,256): leaf.
// blocks [256,256+1026): pack pw (+pb as plane 512) into MFMA A-fragment
// order: set S = (ot*513 + i)*4 + kc  (16 o-tiles x 513 planes x 4 kchunks);
// lane granule = pw[o = ot*32 + (lane&31)][i][l = kc*16 + (lane>>5)*8 + 0..7]
// -> gemm loads each A-frag as ONE coalesced 1KB dwordx4. No LDS for pw.
__global__ __launch_bounds__(256) void prep_kernel(
    const float* __restrict__ x, const float* __restrict__ gw,
    const float* __restrict__ gb, const float* __restrict__ pw,
    const float* __restrict__ pb, float* __restrict__ leaf,
    __bf16* __restrict__ pwb) {
  const int tid = threadIdx.x;
  if (blockIdx.x < 256) {
    const int wid = tid >> 6, lane = tid & 63;
    const int b = blockIdx.x * 4 + wid;
    __shared__ float g[4][NLEAF];
    if (lane < NGATE) {
      const float* xr = x + (size_t)b * INF;
      float a0 = 0.f, a1 = 0.f, a2 = 0.f, a3 = 0.f;
      #pragma unroll 4
      for (int i = 0; i < INF; i += 4) {
        a0 += xr[i + 0] * gw[(i + 0) * NGATE + lane];
        a1 += xr[i + 1] * gw[(i + 1) * NGATE + lane];
        a2 += xr[i + 2] * gw[(i + 2) * NGATE + lane];
        a3 += xr[i + 3] * gw[(i + 3) * NGATE + lane];
      }
      float t = (a0 + a1) + (a2 + a3) + gb[lane];
      g[wid][lane] = 1.0f / (1.0f + __expf(-t));
    }
    __syncthreads();
    float p = 1.0f;
    #pragma unroll
    for (int d = 0; d < TDEPTH; d++) {
      int prefix = lane >> (TDEPTH - 1 - d);
      int node = (1 << d) - 1 + (prefix >> 1);
      float gv = g[wid][node];
      p *= (prefix & 1) ? (1.0f - gv) : gv;
    }
    leaf[(size_t)b * NLEAF + lane] = p;
    return;
  }
  const int bid2 = blockIdx.x - 256;          // 0..1025
  const int w = tid >> 6, lane = tid & 63;
  const int lo = lane & 31, half = lane >> 5;
  #pragma unroll
  for (int it = 0; it < 8; it++) {
    const unsigned S = (unsigned)bid2 * 32 + w * 8 + it;   // < 32832
    const unsigned i_lin = S >> 2, kc = S & 3;
    const unsigned ot = i_lin / 513;
    const unsigned i = i_lin - ot * 513;
    const unsigned o = ot * 32 + lo;
    const unsigned l = kc * 16 + half * 8;
    const float* src = (i < INF) ? (pw + ((size_t)o * INF + i) * NLEAF + l)
                                 : (pb + (size_t)o * NLEAF + l);
    f32x4 a = *(const f32x4*)src;
    f32x4 b = *(const f32x4*)(src + 4);
    *(bf16x8*)((char*)pwb + (size_t)S * 1024 + (size_t)lane * 16) = pack8(a, b);
  }
}

// ---------------- kernel 2: barrier-free swapped-operand GEMM ------------
// D_i[o,b] = sum_l pw[o,i,l]*leaf[b,l] via mfma(A = pw frags from GLOBAL,
// B = leaf resident bf16 regs); acc[o,b] += x[b,i] * D_i (scalar per lane).
// 4 waves/block, each wave an independent 32o x 64b tile. NO barriers in
// the K-loop; pw frags are coalesced 1KB dwordx4 from L2 (XCD-chunked).
__global__ __launch_bounds__(256, 4) void gemm_kernel(
    const __bf16* __restrict__ pwb, const float* __restrict__ x,
    const float* __restrict__ leaf, float* __restrict__ partial) {
  __shared__ __align__(16) float xsm[NPL][64];   // 8 KB, one b-tile

  const int tid = threadIdx.x, lane = tid & 63, w = tid >> 6;
  const int lo = lane & 31, half = lane >> 5;

  // XCD-chunked: L = xcd*128 + idx; s = L>>6 -> each XCD covers 2 s-slices
  // (pwb working set 2 x 2.1 MB = 4.2 MB ~ its L2).
  const int L = ((int)blockIdx.x & 7) * 128 + ((int)blockIdx.x >> 3);
  const int s = L >> 6;
  const int rem = L & 63;
  const int bt = rem & 15, og = rem >> 4;
  const int b0 = bt * 64;
  const int ot = og * 4 + w;                  // this wave's o-tile (32 rows)
  const int oW = ot * 32;
  const int cs = s * NPL;
  const int count = NPL + (s == SPLITK - 1 ? 1 : 0);  // +1 bias plane 512

  // resident leaf B-fragments (bf16): col = b, k-octet = half
  bf16x8 lfb[2][4];
  #pragma unroll
  for (int mt = 0; mt < 2; mt++) {
    const float* lr = leaf + (size_t)(b0 + mt * 32 + lo) * NLEAF + half * 8;
    #pragma unroll
    for (int t4 = 0; t4 < 4; t4++)
      lfb[mt][t4] = pack8(*(const f32x4*)(lr + t4 * 16),
                          *(const f32x4*)(lr + t4 * 16 + 4));
  }

  // this wave's fragment base: frag (t, t4) at + t*4096 + t4*1024 + lane*16
  const char* pwt = (const char*)pwb + ((size_t)(ot * 513 + cs) << 12) +
                    (size_t)lane * 16;

  auto loadB = [&](bf16x8(&B)[4], int t) {
    #pragma unroll
    for (int f = 0; f < 4; f++)
      B[f] = *(const bf16x8*)(pwt + ((size_t)t << 12) + (f << 10));
  };

  f32x16 acc0 = (f32x16)(0.f), acc1 = (f32x16)(0.f);

  bf16x8 Ba[4], Bb[4];
  loadB(Ba, 0);
  loadB(Bb, 1);

  // stage x slice (shared by all 4 waves): xsm[plane][brow], f32
  {
    const int r = tid >> 2, c8 = (tid & 3) * 8;
    const float* src = x + (size_t)(b0 + r) * INF + cs + c8;
    f32x4 v0 = *(const f32x4*)src;
    f32x4 v1 = *(const f32x4*)(src + 4);
    #pragma unroll
    for (int j = 0; j < 4; j++) xsm[c8 + j][r] = v0[j];
    #pragma unroll
    for (int j = 0; j < 4; j++) xsm[c8 + 4 + j][r] = v1[j];
  }
  __syncthreads();

  auto step = [&](const bf16x8(&B)[4], int t) {
    float xv0 = 1.0f, xv1 = 1.0f;
    if (t < NPL) {
      xv0 = xsm[t][lo];
      xv1 = xsm[t][32 + lo];
    }
    {
      f32x16 D = (f32x16)(0.f);
      #pragma unroll
      for (int t4 = 0; t4 < 4; t4++)
        D = __builtin_amdgcn_mfma_f32_32x32x16_bf16(B[t4], lfb[0][t4], D, 0, 0, 0);
      acc0 += D * xv0;
    }
    {
      f32x16 D = (f32x16)(0.f);
      #pragma unroll
      for (int t4 = 0; t4 < 4; t4++)
        D = __builtin_amdgcn_mfma_f32_32x32x16_bf16(B[t4], lfb[1][t4], D, 0, 0, 0);
      acc1 += D * xv1;
    }
  };

  int t = 0;
  while (t < count) {
    step(Ba, t);
    if (t + 2 < count) loadB(Ba, t + 2);
    if (++t >= count) break;
    step(Bb, t);
    if (t + 2 < count) loadB(Bb, t + 2);
    ++t;
  }

  // epilogue: partial[s][o][b] (transposed), coalesced over b = lo
  float* dstb = partial + ((size_t)s * OUTF + oW) * BATCH + b0;
  #pragma unroll
  for (int e = 0; e < 16; e++) {
    int row = (e & 3) + 8 * (e >> 2) + 4 * half;   // o within the 32-tile
    dstb[(size_t)row * BATCH + lo] = acc0[e];
    dstb[(size_t)row * BATCH + 32 + lo] = acc1[e];
  }
}

// ---------------- kernel 3: split-K reduce + transpose ----------------
// partial[s][o][b] -> out[b][o]
__global__ __launch_bounds__(256) void reduce_kernel(
    const float* __restrict__ partial, float* __restrict__ out) {
  __shared__ float tile[32][65];
  const int t = threadIdx.x;
  const int O0 = ((int)blockIdx.x >> 4) * 32;
  const int B0 = ((int)blockIdx.x & 15) * 64;
  #pragma unroll
  for (int rep = 0; rep < 8; rep++) {
    const int idx = rep * 256 + t;
    const int o = idx >> 6, b = idx & 63;
    float sum = 0.f;
    #pragma unroll
    for (int s = 0; s < SPLITK; s++)
      sum += partial[((size_t)s * OUTF + O0 + o) * BATCH + B0 + b];
    tile[o][b] = sum;
  }
  __syncthreads();
  #pragma unroll
  for (int rep = 0; rep < 8; rep++) {
    const int idx = rep * 256 + t;
    const int b = idx >> 5, o = idx & 31;
    out[(size_t)(B0 + b) * OUTF + O0 + o] = tile[o][b];
  }
}

extern "C" void kernel_launch(void* const* d_in, const int* in_sizes, int n_in,
                              void* d_out, int out_size, void* d_ws, size_t ws_size,
                              hipStream_t stream) {
  const float* x  = (const float*)d_in[0];
  const float* gw = (const float*)d_in[1];
  const float* gb = (const float*)d_in[2];
  const float* pw = (const float*)d_in[3];
  const float* pb = (const float*)d_in[4];
  float* out = (float*)d_out;

  float*  leaf    = (float*)d_ws;                            // 256 KB
  __bf16* pwb     = (__bf16*)((char*)d_ws + (256 << 10));    // 33.6 MB
  float*  partial = (float*)((char*)d_ws + (256 << 10) + (size_t)16 * 513 * 4096);

  prep_kernel<<<256 + 1026, 256, 0, stream>>>(x, gw, gb, pw, pb, leaf, pwb);
  gemm_kernel<<<1024, 256, 0, stream>>>(pwb, x, leaf, partial);
  reduce_kernel<<<256, 256, 0, stream>>>(partial, out);
}

// Round 16
// 72.141 us; speedup vs baseline: 2.7289x; 2.7289x over previous
//
#include <hip/hip_runtime.h>
#include <hip/hip_bf16.h>

#define TDEPTH 6
#define NLEAF 64
#define NGATE 63
#define INF 512
#define OUTF 512
#define BATCH 1024
#define SPLITK 8
#define NPL 64        // real planes per K-slice (512/SPLITK)

typedef _Float16 f16;
typedef __attribute__((ext_vector_type(2)))  f16 f16x2;
typedef __attribute__((ext_vector_type(8)))  f16 f16x8;
typedef __attribute__((ext_vector_type(4)))  float f32x4;
typedef __attribute__((ext_vector_type(16))) float f32x16;

__device__ __forceinline__ f16x8 pack8h(f32x4 a, f32x4 b) {
  f16x8 w;
  w[0] = (f16)a[0]; w[1] = (f16)a[1]; w[2] = (f16)a[2]; w[3] = (f16)a[3];
  w[4] = (f16)b[0]; w[5] = (f16)b[1]; w[6] = (f16)b[2]; w[7] = (f16)b[3];
  return w;
}

// ---------------- kernel 1: leaf probs + pwh pack ----------------
// blocks [0,256): leaf.  blocks [256,256+8208): pack pw (+pb as plane 512)
// into f16 4KB tiles per (ot, i): [16 rows][16 granules]; granule at (r,p)
// holds v = p^r -> o = ot*32 + r + 16*(v>>3), k-granule kg = v&7.
// Gemm stages tiles LINEARLY via gload_lds; reads conflict-free with
// byte = (lo&15)*256 + (inner ^ ((lo&15)<<4)).
__global__ __launch_bounds__(256) void prep_kernel(
    const float* __restrict__ x, const float* __restrict__ gw,
    const float* __restrict__ gb, const float* __restrict__ pw,
    const float* __restrict__ pb, float* __restrict__ leaf,
    f16* __restrict__ pwh) {
  const int tid = threadIdx.x;
  if (blockIdx.x < 256) {
    const int wid = tid >> 6, lane = tid & 63;
    const int b = blockIdx.x * 4 + wid;
    __shared__ float g[4][NLEAF];
    if (lane < NGATE) {
      const float* xr = x + (size_t)b * INF;
      float a0 = 0.f, a1 = 0.f, a2 = 0.f, a3 = 0.f;
      #pragma unroll 4
      for (int i = 0; i < INF; i += 4) {
        a0 += xr[i + 0] * gw[(i + 0) * NGATE + lane];
        a1 += xr[i + 1] * gw[(i + 1) * NGATE + lane];
        a2 += xr[i + 2] * gw[(i + 2) * NGATE + lane];
        a3 += xr[i + 3] * gw[(i + 3) * NGATE + lane];
      }
      float t = (a0 + a1) + (a2 + a3) + gb[lane];
      g[wid][lane] = 1.0f / (1.0f + __expf(-t));
    }
    __syncthreads();
    float p = 1.0f;
    #pragma unroll
    for (int d = 0; d < TDEPTH; d++) {
      int prefix = lane >> (TDEPTH - 1 - d);
      int node = (1 << d) - 1 + (prefix >> 1);
      float gv = g[wid][node];
      p *= (prefix & 1) ? (1.0f - gv) : gv;
    }
    leaf[(size_t)b * NLEAF + lane] = p;
    return;
  }
  const unsigned Q = (blockIdx.x - 256) * 256 + tid;  // granule id
  const unsigned tile = Q >> 8;            // ot*513 + i
  const unsigned ot = tile / 513;
  const unsigned i = tile - ot * 513;
  const unsigned q = Q & 255;
  const unsigned r = q >> 4, p = q & 15;
  const unsigned v = p ^ r;
  const unsigned o = ot * 32 + r + 16 * (v >> 3);
  const unsigned kg = v & 7;
  const float* src = (i < INF) ? (pw + ((size_t)o * INF + i) * NLEAF + kg * 8)
                               : (pb + (size_t)o * NLEAF + kg * 8);
  f32x4 a = *(const f32x4*)src, b = *(const f32x4*)(src + 4);
  *(f16x8*)((char*)pwh + (size_t)Q * 16) = pack8h(a, b);
}

// async 16B global -> LDS (wave-uniform LDS base; +lane*16 implicit)
__device__ __forceinline__ void gload_lds16(const void* g, void* l) {
  __builtin_amdgcn_global_load_lds(
      (const __attribute__((address_space(1))) void*)g,
      (__attribute__((address_space(3))) void*)l, 16, 0, 0);
}

// ---------------- kernel 2: barrier-free 1-wave GEMM ----------------
// acc[o,b] += sum_l pw[o,i,l] * (x[b,i]*leaf[b,l])  via
// mfma(A = pw frag from LDS, B = lfb * xv8 (v_pk_mul_f16), C = acc direct).
// 1 wave/block; NO s_barrier in the K-loop; 3 LDS tile buffers staged with
// gload_lds; counted s_waitcnt vmcnt(8) (never 0 mid-loop).
__global__ __launch_bounds__(64, 2) void gemm_kernel(
    const f16* __restrict__ pwh, const float* __restrict__ x,
    const float* __restrict__ leaf, float* __restrict__ partial) {
  __shared__ __align__(16) char Bsm[3][4096];
  __shared__ unsigned short xsm[NPL][64];   // f16 bits, 8 KB

  const int lane = threadIdx.x;
  const int lo = lane & 31, half = lane >> 5;

  // XCD-chunked: per XCD 256 blocks cover 16 (ot,s) pairs (4.2MB ~ L2)
  const int L = ((int)blockIdx.x & 7) * 256 + ((int)blockIdx.x >> 3);
  const int bt = L & 15;
  const int p = L >> 4;               // 0..127
  const int ot = p & 15, s = p >> 4;  // 16 o-tiles x 8 slices
  const int b0 = bt * 64;
  const int cs = s * NPL;
  const int count = NPL + (s == SPLITK - 1 ? 1 : 0);  // +1 bias plane 512

  // stage x slice -> f16 bits [plane][b]; lane = b-row
  {
    const float* xr = x + (size_t)(b0 + lane) * INF + cs;
    #pragma unroll
    for (int c4 = 0; c4 < NPL / 4; c4++) {
      f32x4 v = *(const f32x4*)(xr + c4 * 4);
      #pragma unroll
      for (int j = 0; j < 4; j++)
        xsm[c4 * 4 + j][lane] = __builtin_bit_cast(unsigned short, (f16)v[j]);
    }
  }

  // resident leaf B-fragments (f16): col = b, k-octet = half
  f16x8 lfb[2][4];
  #pragma unroll
  for (int mt = 0; mt < 2; mt++) {
    const float* lr = leaf + (size_t)(b0 + mt * 32 + lo) * NLEAF + half * 8;
    #pragma unroll
    for (int t4 = 0; t4 < 4; t4++)
      lfb[mt][t4] = pack8h(*(const f32x4*)(lr + t4 * 16),
                           *(const f32x4*)(lr + t4 * 16 + 4));
  }

  // per-lane LDS read offsets (loop-invariant): A-frag (o=lo, chunk t4)
  unsigned rdoff[4];
  {
    const unsigned r = (unsigned)(lo & 15);
    const unsigned hb = ((unsigned)(lo >> 4)) * 128 + (unsigned)half * 16;
    #pragma unroll
    for (int t4 = 0; t4 < 4; t4++)
      rdoff[t4] = r * 256 + ((hb + t4 * 32) ^ (r << 4));
  }

  const char* tb = (const char*)pwh + ((size_t)(ot * 513 + cs) << 12) +
                   (size_t)lane * 16;
  auto stage = [&](char* dstb, int t) {
    const char* srcb = tb + ((size_t)t << 12);
    #pragma unroll
    for (int j = 0; j < 4; j++)
      gload_lds16(srcb + j * 1024, dstb + j * 1024);
  };

  f32x16 acc0 = (f32x16)(0.f), acc1 = (f32x16)(0.f);

  auto do_step = [&](const char* bufc, int t) {
    unsigned pr0 = 0x3C003C00u, pr1 = 0x3C003C00u;  // f16 1.0 pair (bias)
    if (t < NPL) {
      unsigned x0 = xsm[t][lo], x1 = xsm[t][32 + lo];
      pr0 = x0 | (x0 << 16);
      pr1 = x1 | (x1 << 16);
    }
    f16x2 v0 = __builtin_bit_cast(f16x2, pr0);
    f16x2 v1 = __builtin_bit_cast(f16x2, pr1);
    f16x8 xv80 = __builtin_shufflevector(v0, v0, 0, 1, 0, 1, 0, 1, 0, 1);
    f16x8 xv81 = __builtin_shufflevector(v1, v1, 0, 1, 0, 1, 0, 1, 0, 1);
    #pragma unroll
    for (int t4 = 0; t4 < 4; t4++) {
      f16x8 af = *(const f16x8*)(bufc + rdoff[t4]);
      f16x8 s0 = lfb[0][t4] * xv80;   // 4 x v_pk_mul_f16
      f16x8 s1 = lfb[1][t4] * xv81;
      acc0 = __builtin_amdgcn_mfma_f32_32x32x16_f16(af, s0, acc0, 0, 0, 0);
      acc1 = __builtin_amdgcn_mfma_f32_32x32x16_f16(af, s1, acc1, 0, 0, 0);
    }
  };

  char* bA = (char*)&Bsm[0][0];
  char* bB = (char*)&Bsm[1][0];
  char* bC = (char*)&Bsm[2][0];

  stage(bA, 0);
  stage(bB, 1);
  asm volatile("s_waitcnt lgkmcnt(0)" ::: "memory");  // xsm writes done

  for (int t = 0; t < count - 2; ++t) {
    stage(bC, t + 2);
    asm volatile("s_waitcnt vmcnt(8)" ::: "memory");  // stage(t) landed
    do_step(bA, t);
    char* tmp = bA; bA = bB; bB = bC; bC = tmp;
  }
  asm volatile("s_waitcnt vmcnt(4)" ::: "memory");
  do_step(bA, count - 2);
  asm volatile("s_waitcnt vmcnt(0)" ::: "memory");
  do_step(bB, count - 1);

  // epilogue: partial[s][o][b] (transposed), coalesced over b = lo
  float* dstb = partial + ((size_t)s * OUTF + ot * 32) * BATCH + b0;
  #pragma unroll
  for (int e = 0; e < 16; e++) {
    int row = (e & 3) + 8 * (e >> 2) + 4 * half;   // o within the 32-tile
    dstb[(size_t)row * BATCH + lo] = acc0[e];
    dstb[(size_t)row * BATCH + 32 + lo] = acc1[e];
  }
}

// ---------------- kernel 3: split-K reduce + transpose ----------------
// partial[s][o][b] -> out[b][o]
__global__ __launch_bounds__(256) void reduce_kernel(
    const float* __restrict__ partial, float* __restrict__ out) {
  __shared__ float tile[32][65];
  const int t = threadIdx.x;
  const int O0 = ((int)blockIdx.x >> 4) * 32;
  const int B0 = ((int)blockIdx.x & 15) * 64;
  #pragma unroll
  for (int rep = 0; rep < 8; rep++) {
    const int idx = rep * 256 + t;
    const int o = idx >> 6, b = idx & 63;
    float sum = 0.f;
    #pragma unroll
    for (int s = 0; s < SPLITK; s++)
      sum += partial[((size_t)s * OUTF + O0 + o) * BATCH + B0 + b];
    tile[o][b] = sum;
  }
  __syncthreads();
  #pragma unroll
  for (int rep = 0; rep < 8; rep++) {
    const int idx = rep * 256 + t;
    const int b = idx >> 5, o = idx & 31;
    out[(size_t)(B0 + b) * OUTF + O0 + o] = tile[o][b];
  }
}

extern "C" void kernel_launch(void* const* d_in, const int* in_sizes, int n_in,
                              void* d_out, int out_size, void* d_ws, size_t ws_size,
                              hipStream_t stream) {
  const float* x  = (const float*)d_in[0];
  const float* gw = (const float*)d_in[1];
  const float* gb = (const float*)d_in[2];
  const float* pw = (const float*)d_in[3];
  const float* pb = (const float*)d_in[4];
  float* out = (float*)d_out;

  float* leaf    = (float*)d_ws;                          // 256 KB
  f16*   pwh     = (f16*)((char*)d_ws + (256 << 10));     // 33.62 MB
  float* partial = (float*)((char*)d_ws + (256 << 10) + (size_t)16 * 513 * 4096);

  prep_kernel<<<256 + 8208, 256, 0, stream>>>(x, gw, gb, pw, pb, leaf, pwh);
  gemm_kernel<<<2048, 64, 0, stream>>>(pwh, x, leaf, partial);
  reduce_kernel<<<256, 256, 0, stream>>>(partial, out);
}